// Round 2
// baseline (306.547 us; speedup 1.0000x reference)
//
#include <hip/hip_runtime.h>

#define NEG_SLOPE 0.01f

constexpr int N_NODES_C = 50000;
constexpr int N_EDGES_C = 800000;
constexpr int M_PAD = 50048;  // 391 * 128

typedef short bf16x8 __attribute__((ext_vector_type(8)));
typedef float f32x4 __attribute__((ext_vector_type(4)));

__device__ inline unsigned short f2bf(float f) {
  unsigned int u = __float_as_uint(f);
  u += 0x7FFF + ((u >> 16) & 1);  // round-to-nearest-even
  return (unsigned short)(u >> 16);
}
__device__ inline float bf2f(unsigned int h16) {
  return __uint_as_float(h16 << 16);
}

// ---------------- fused preprocessing ----------------
constexpr int NB_CONVX = (M_PAD * 32) / 256;          // 6256
constexpr int NB_W1 = (256 * 256) / 256;              // 256
constexpr int NB_W2 = (256 * 128) / 256;              // 128
// histogram: 4 edges/thread, int4 loads (800000 % 4 == 0 -> no partial groups)
constexpr int NB_HIST = ((N_EDGES_C / 4) + 255) / 256;  // 782
constexpr int NB_PRE = NB_CONVX + NB_W1 + NB_W2 + NB_HIST;

__global__ __launch_bounds__(256) void pre_kernel(
    const float* __restrict__ x, const float* __restrict__ w1,
    const float* __restrict__ w2, const int* __restrict__ dst,
    unsigned short* __restrict__ xb, unsigned short* __restrict__ w1T,
    unsigned short* __restrict__ w2T, int* __restrict__ counts) {
  const int bx = blockIdx.x;
  const int tid = threadIdx.x;
  if (bx < NB_CONVX) {
    int idx = bx * 256 + tid;
    int row = idx >> 5;
    int c8 = (idx & 31) << 3;
    uint4 v;
    if (row < N_NODES_C) {
      const float4* p = (const float4*)(x + (size_t)row * 256 + c8);
      float4 a = p[0], b = p[1];
      v.x = f2bf(a.x) | ((unsigned)f2bf(a.y) << 16);
      v.y = f2bf(a.z) | ((unsigned)f2bf(a.w) << 16);
      v.z = f2bf(b.x) | ((unsigned)f2bf(b.y) << 16);
      v.w = f2bf(b.z) | ((unsigned)f2bf(b.w) << 16);
    } else {
      v = make_uint4(0, 0, 0, 0);
    }
    *(uint4*)(xb + (size_t)row * 256 + c8) = v;
  } else if (bx < NB_CONVX + NB_W1) {
    int idx = (bx - NB_CONVX) * 256 + tid;  // over [N=256][K=256]
    int n = idx >> 8, k = idx & 255;
    w1T[idx] = f2bf(w1[(size_t)k * 256 + n]);
  } else if (bx < NB_CONVX + NB_W1 + NB_W2) {
    int idx = (bx - NB_CONVX - NB_W1) * 256 + tid;  // over [N=128][K=256]
    int n = idx >> 8, k = idx & 255;
    w2T[idx] = f2bf(w2[(size_t)k * 128 + n]);
  } else {
    // 4-edge ILP histogram: independent atomics, vectorized index load
    int g = (bx - NB_CONVX - NB_W1 - NB_W2) * 256 + tid;
    int e = g * 4;
    if (e < N_EDGES_C) {
      int4 d4 = *(const int4*)(dst + e);
      atomicAdd(&counts[d4.x], 1);
      atomicAdd(&counts[d4.y], 1);
      atomicAdd(&counts[d4.z], 1);
      atomicAdd(&counts[d4.w], 1);
    }
  }
}

// ---------------- hierarchical scan (2 launches) ----------------
constexpr int N_SCAN_BLKS = (N_NODES_C + 255) / 256;  // 196

__global__ __launch_bounds__(256) void scan_phase_a(const int* __restrict__ counts,
                                                    int* __restrict__ partial,
                                                    int* __restrict__ blk_sums,
                                                    int* __restrict__ hist2) {
  __shared__ int s[256];
  __shared__ int lh[64];
  const int t = threadIdx.x;
  const int i = blockIdx.x * 256 + t;
  const int v = (i < N_NODES_C) ? counts[i] : 0;
  s[t] = v;
  if (t < 64) lh[t] = 0;
  __syncthreads();
  for (int off = 1; off < 256; off <<= 1) {
    int u = (t >= off) ? s[t - off] : 0;
    __syncthreads();
    s[t] += u;
    __syncthreads();
  }
  if (i < N_NODES_C) {
    partial[i] = s[t] - v;
    atomicAdd(&lh[v < 63 ? v : 63], 1);  // degree histogram (LDS-local)
  }
  if (t == 255) blk_sums[blockIdx.x] = s[255];
  __syncthreads();
  if (t < 64) {
    int c = lh[t];
    if (c) atomicAdd(&hist2[t], c);
  }
}

// each block redundantly scans the 196 block sums, then adds its own offset.
// block 0's wave 0 additionally scans the 64-bin degree histogram -> cursor2.
__global__ __launch_bounds__(256) void scan_phase_bc(const int* __restrict__ partial,
                                                     const int* __restrict__ blk_sums,
                                                     int* __restrict__ row_ptr,
                                                     int* __restrict__ cursor,
                                                     const int* __restrict__ hist2,
                                                     int* __restrict__ cursor2) {
  __shared__ int s[256];
  __shared__ int blk_excl;
  const int t = threadIdx.x;
  const int v = (t < N_SCAN_BLKS) ? blk_sums[t] : 0;
  s[t] = v;
  __syncthreads();
  for (int off = 1; off < 256; off <<= 1) {
    int u = (t >= off) ? s[t - off] : 0;
    __syncthreads();
    s[t] += u;
    __syncthreads();
  }
  if (t == (int)blockIdx.x) blk_excl = s[t] - v;  // this block's exclusive offset
  __syncthreads();
  const int i = blockIdx.x * 256 + t;
  if (i < N_NODES_C) {
    const int r = partial[i] + blk_excl;
    row_ptr[i] = r;
    cursor[i] = r;
  }
  if (i == 0) row_ptr[N_NODES_C] = N_EDGES_C;
  if (blockIdx.x == 0 && t < 64) {
    int hv = hist2[t];
    int x = hv;
#pragma unroll
    for (int off = 1; off < 64; off <<= 1) {
      int u = __shfl_up(x, off);
      if (t >= off) x += u;
    }
    cursor2[t] = x - hv;  // exclusive bucket offsets
  }
}

// ---------------- shared GEMM tile (device fn) ----------------
// C_sliced[slice][M_PAD][32] where slice = col/32

#define GLOAD_LDS16(g, l)                                              \
  __builtin_amdgcn_global_load_lds(                                    \
      (__attribute__((address_space(1))) void*)(g),                    \
      (__attribute__((address_space(3))) void*)(l), 16, 0, 0)

__device__ __forceinline__ void gemm_tile(
    const unsigned short* __restrict__ A,   // [M_PAD][256] bf16
    const unsigned short* __restrict__ BT,  // [N][256] bf16
    unsigned short* __restrict__ C,         // [N/32][M_PAD][32] sliced
    int N, int row0, int col0, short* Asm, short* Bsm) {
  constexpr int K = 256;
  const int tid = threadIdx.x;
  const int lane = tid & 63, wave = tid >> 6;
  const int wm = wave & 1, wn = wave >> 1;

  const int ch0 = wave * 2, ch1 = wave * 2 + 1;
  const int o0 = ch0 * 512 + lane * 8;
  const int o1 = ch1 * 512 + lane * 8;
  const int r0 = o0 >> 5, c0 = o0 & 31;
  const int r1 = o1 >> 5, c1 = o1 & 31;

  f32x4 acc[4][4] = {};

  for (int k0 = 0; k0 < K; k0 += 32) {
    GLOAD_LDS16(A + (size_t)(row0 + r0) * K + k0 + c0, &Asm[ch0 * 512]);
    GLOAD_LDS16(A + (size_t)(row0 + r1) * K + k0 + c1, &Asm[ch1 * 512]);
    GLOAD_LDS16(BT + (size_t)(col0 + r0) * K + k0 + c0, &Bsm[ch0 * 512]);
    GLOAD_LDS16(BT + (size_t)(col0 + r1) * K + k0 + c1, &Bsm[ch1 * 512]);
    __builtin_amdgcn_s_waitcnt(0);
    __syncthreads();

    bf16x8 af[4], bf[4];
#pragma unroll
    for (int mt = 0; mt < 4; ++mt)
      af[mt] = *(const bf16x8*)&Asm[(wm * 64 + mt * 16 + (lane & 15)) * 32 + (lane >> 4) * 8];
#pragma unroll
    for (int nt = 0; nt < 4; ++nt)
      bf[nt] = *(const bf16x8*)&Bsm[(wn * 64 + nt * 16 + (lane & 15)) * 32 + (lane >> 4) * 8];
#pragma unroll
    for (int mt = 0; mt < 4; ++mt)
#pragma unroll
      for (int nt = 0; nt < 4; ++nt)
        acc[mt][nt] = __builtin_amdgcn_mfma_f32_16x16x32_bf16(af[mt], bf[nt], acc[mt][nt], 0, 0, 0);
    __syncthreads();
  }

  const int cl = lane & 15, rq = (lane >> 4) * 4;
#pragma unroll
  for (int mt = 0; mt < 4; ++mt) {
    const int rbase = row0 + wm * 64 + mt * 16 + rq;
#pragma unroll
    for (int nt = 0; nt < 4; ++nt) {
      const int col = col0 + wn * 64 + nt * 16 + cl;
      const size_t sbase = ((size_t)(col >> 5) * M_PAD) * 32 + (col & 31);
#pragma unroll
      for (int i = 0; i < 4; ++i)
        C[sbase + (size_t)(rbase + i) * 32] = f2bf(acc[mt][nt][i]);
    }
  }
}

// ---------------- fused fill + gemm1 + perm-scatter ----------------
// b < 1564: even = gemm1 tile, odd = CSR bucket fill (4 edges/thread).
// b >= 1564: degree-sorted permutation scatter (LDS rank + 1 atomic/bin/block).
// meta packed 4B: src(u16) | bf16(ew)<<16
constexpr int NB_GEMM1 = 2 * (M_PAD / 128);              // 782
constexpr int NB_FILL = ((N_EDGES_C / 4) + 255) / 256;   // 782 (== NB_GEMM1)
constexpr int NB_SCAT = (M_PAD + 255) / 256;             // 196

__global__ __launch_bounds__(256) void fill_gemm1_kernel(
    const unsigned short* __restrict__ A, const unsigned short* __restrict__ BT,
    unsigned short* __restrict__ C, const int* __restrict__ src,
    const int* __restrict__ dst, const float* __restrict__ ew,
    int* __restrict__ cursor, unsigned* __restrict__ s_meta,
    const int* __restrict__ counts, int* __restrict__ cursor2,
    int* __restrict__ perm) {
  __shared__ short Asm[128 * 32];
  __shared__ short Bsm[128 * 32];
  __shared__ int lhist[64];
  __shared__ int lbase[64];
  const int b = blockIdx.x;
  if (b < NB_GEMM1 + NB_FILL) {
    if ((b & 1) == 0) {
      const int t = b >> 1;  // [0, NB_GEMM1)
      gemm_tile(A, BT, C, 256, (t >> 1) * 128, (t & 1) * 128, Asm, Bsm);
    } else {
      const int g = (b >> 1) * 256 + threadIdx.x;  // 4-edge group id
      const int e = g * 4;
      if (e < N_EDGES_C) {
        int4 d4 = *(const int4*)(dst + e);
        int4 s4 = *(const int4*)(src + e);
        float4 w4 = *(const float4*)(ew + e);
        unsigned m0 = (unsigned)s4.x | ((unsigned)f2bf(w4.x) << 16);
        unsigned m1 = (unsigned)s4.y | ((unsigned)f2bf(w4.y) << 16);
        unsigned m2 = (unsigned)s4.z | ((unsigned)f2bf(w4.z) << 16);
        unsigned m3 = (unsigned)s4.w | ((unsigned)f2bf(w4.w) << 16);
        int p0 = atomicAdd(&cursor[d4.x], 1);
        int p1 = atomicAdd(&cursor[d4.y], 1);
        int p2 = atomicAdd(&cursor[d4.z], 1);
        int p3 = atomicAdd(&cursor[d4.w], 1);
        __builtin_nontemporal_store(m0, s_meta + p0);
        __builtin_nontemporal_store(m1, s_meta + p1);
        __builtin_nontemporal_store(m2, s_meta + p2);
        __builtin_nontemporal_store(m3, s_meta + p3);
      }
    }
  } else {
    const int t = threadIdx.x;
    if (t < 64) lhist[t] = 0;
    __syncthreads();
    const int idx = (b - NB_GEMM1 - NB_FILL) * 256 + t;
    int d = -1, lrank = 0;
    if (idx < N_NODES_C) {
      d = counts[idx];
      if (d > 63) d = 63;
      lrank = atomicAdd(&lhist[d], 1);  // intra-block rank within bin
    } else if (idx < M_PAD) {
      perm[idx] = idx;  // padding rows map to themselves
    }
    __syncthreads();
    if (t < 64) {
      int c = lhist[t];
      lbase[t] = c ? atomicAdd(&cursor2[t], c) : 0;  // one global atomic/bin
    }
    __syncthreads();
    if (d >= 0) perm[lbase[d] + lrank] = idx;
  }
}

__global__ __launch_bounds__(256) void gemm2_kernel(
    const unsigned short* __restrict__ A, const unsigned short* __restrict__ BT,
    unsigned short* __restrict__ C) {
  __shared__ short Asm[128 * 32];
  __shared__ short Bsm[128 * 32];
  gemm_tile(A, BT, C, 128, blockIdx.x * 128, 0, Asm, Bsm);
}

// ---------------- lite sliced aggregation ----------------
// ONE WAVE per block (64 thr) = 16 quad-nodes; slice = bx & (NSLICE-1) with
// slice-innermost ordering (table slice stays L2-resident).
// Nodes taken through degree-sorted perm -> uniform trip counts per wave
// (kills the ~1.6x Poisson max-of-16 divergence inflation).
// 4 lanes per node; lane owns 8 dims; 4-edge unroll for gather MLP.

__device__ inline void fma8(float* acc, uint4 v, float wt) {
  acc[0] += bf2f(v.x & 0xffffu) * wt;
  acc[1] += bf2f(v.x >> 16) * wt;
  acc[2] += bf2f(v.y & 0xffffu) * wt;
  acc[3] += bf2f(v.y >> 16) * wt;
  acc[4] += bf2f(v.z & 0xffffu) * wt;
  acc[5] += bf2f(v.z >> 16) * wt;
  acc[6] += bf2f(v.w & 0xffffu) * wt;
  acc[7] += bf2f(v.w >> 16) * wt;
}

template <int NSLICE, int OUT_D, bool OUT_BF16>
__global__ __launch_bounds__(64) void agg_lite_kernel(
    const unsigned short* __restrict__ supS,  // [NSLICE][M_PAD][32]
    const unsigned* __restrict__ s_meta,      // src u16 | bf16(ew) << 16
    const int* __restrict__ row_ptr, const float* __restrict__ bias,
    const int* __restrict__ perm,
    unsigned short* __restrict__ out_bf, float* __restrict__ out_f, int n_total) {
  const int bx = blockIdx.x;
  const int slice = bx & (NSLICE - 1);
  const int group = bx / NSLICE;
  const int lane = threadIdx.x;  // 0..63
  const int quad = lane >> 2;    // node within group (0..15)
  const int dimg = lane & 3;     // 8-dim octet within 32-dim slice
  const int idx = group * 16 + quad;
  if (idx >= n_total) return;
  const int n = perm[idx];
  const bool valid = n < N_NODES_C;
  const unsigned short* tab = supS + (size_t)slice * M_PAD * 32;

  float acc[8] = {};
  if (valid) {
    int j = row_ptr[n];
    const int end = row_ptr[n + 1];
    for (; j + 4 <= end; j += 4) {
      unsigned m0 = s_meta[j];
      unsigned m1 = s_meta[j + 1];
      unsigned m2 = s_meta[j + 2];
      unsigned m3 = s_meta[j + 3];
      uint4 v0 = *(const uint4*)(tab + (m0 & 0xffffu) * 32 + dimg * 8);
      uint4 v1 = *(const uint4*)(tab + (m1 & 0xffffu) * 32 + dimg * 8);
      uint4 v2 = *(const uint4*)(tab + (m2 & 0xffffu) * 32 + dimg * 8);
      uint4 v3 = *(const uint4*)(tab + (m3 & 0xffffu) * 32 + dimg * 8);
      fma8(acc, v0, bf2f(m0 >> 16));
      fma8(acc, v1, bf2f(m1 >> 16));
      fma8(acc, v2, bf2f(m2 >> 16));
      fma8(acc, v3, bf2f(m3 >> 16));
    }
    for (; j < end; ++j) {
      unsigned m0 = s_meta[j];
      uint4 v0 = *(const uint4*)(tab + (m0 & 0xffffu) * 32 + dimg * 8);
      fma8(acc, v0, bf2f(m0 >> 16));
    }
  }

  const int dbase = slice * 32 + dimg * 8;
  if (OUT_BF16) {
    unsigned short o[8];
#pragma unroll
    for (int j = 0; j < 8; ++j) {
      if (valid) {
        float v = acc[j] + bias[dbase + j];
        v = v >= 0.f ? v : NEG_SLOPE * v;
        o[j] = f2bf(v);
      } else {
        o[j] = 0;
      }
    }
    uint4 pk;
    pk.x = o[0] | ((unsigned)o[1] << 16);
    pk.y = o[2] | ((unsigned)o[3] << 16);
    pk.z = o[4] | ((unsigned)o[5] << 16);
    pk.w = o[6] | ((unsigned)o[7] << 16);
    *(uint4*)(out_bf + (size_t)n * OUT_D + dbase) = pk;
  } else if (valid) {
    float r[8];
#pragma unroll
    for (int j = 0; j < 8; ++j) {
      float v = acc[j] + bias[dbase + j];
      r[j] = v >= 0.f ? v : NEG_SLOPE * v;
    }
    *(float4*)(out_f + (size_t)n * OUT_D + dbase) = make_float4(r[0], r[1], r[2], r[3]);
    *(float4*)(out_f + (size_t)n * OUT_D + dbase + 4) = make_float4(r[4], r[5], r[6], r[7]);
  }
}

// ---------------- launch ----------------

extern "C" void kernel_launch(void* const* d_in, const int* in_sizes, int n_in,
                              void* d_out, int out_size, void* d_ws, size_t ws_size,
                              hipStream_t stream) {
  const float* x  = (const float*)d_in[0];   // [50000,256]
  const float* w1 = (const float*)d_in[1];   // [256,256]
  const float* b1 = (const float*)d_in[2];   // [256]
  const float* w2 = (const float*)d_in[3];   // [256,128]
  const float* b2 = (const float*)d_in[4];   // [128]
  const int*   src = (const int*)d_in[5];    // [800000]
  const int*   dst = (const int*)d_in[6];    // [800000]
  const float* ew  = (const float*)d_in[7];  // [800000]
  float* out = (float*)d_out;                // [50000,128]

  unsigned short* xb   = (unsigned short*)d_ws;              // M_PAD*256
  unsigned short* a2b  = xb + (size_t)M_PAD * 256;           // M_PAD*256
  unsigned short* sup1 = a2b + (size_t)M_PAD * 256;          // 8 x [M_PAD][32]
  unsigned short* sup2 = sup1 + (size_t)M_PAD * 256;         // 4 x [M_PAD][32]
  unsigned short* w1T  = sup2 + (size_t)M_PAD * 128;         // 256*256
  unsigned short* w2T  = w1T + 256 * 256;                    // 128*256
  int* counts  = (int*)(w2T + 128 * 256);                    // 50000
  int* cursor  = counts + N_NODES_C;                         // 50000
  int* row_ptr = cursor + N_NODES_C;                         // 50001
  int* partial = row_ptr + (N_NODES_C + 1);                  // 50000
  int* blk_sums= partial + N_NODES_C;                        // 256
  unsigned* s_meta = (unsigned*)(blk_sums + 256);            // 800000 * 4B
  int* hist2   = (int*)(s_meta + N_EDGES_C);                 // 64
  int* cursor2 = hist2 + 64;                                 // 64
  int* perm    = cursor2 + 64;                               // M_PAD

  // preprocessing: zero counts+hist, then fused {conv_x, w1T, w2T, histogram}
  hipMemsetAsync(counts, 0, N_NODES_C * sizeof(int), stream);
  hipMemsetAsync(hist2, 0, 64 * sizeof(int), stream);
  pre_kernel<<<NB_PRE, 256, 0, stream>>>(x, w1, w2, dst, xb, w1T, w2T, counts);

  // CSR scan (+ degree histogram, + 64-bin bucket scan)
  scan_phase_a<<<N_SCAN_BLKS, 256, 0, stream>>>(counts, partial, blk_sums, hist2);
  scan_phase_bc<<<N_SCAN_BLKS, 256, 0, stream>>>(partial, blk_sums, row_ptr, cursor,
                                                 hist2, cursor2);

  // fused: CSR bucket fill + gemm1 + degree-sort scatter (one dispatch)
  fill_gemm1_kernel<<<NB_GEMM1 + NB_FILL + NB_SCAT, 256, 0, stream>>>(
      xb, w1T, sup1, src, dst, ew, cursor, s_meta, counts, cursor2, perm);

  // layer-1 aggregation -> a2b (bf16, lrelu+bias fused)
  agg_lite_kernel<8, 256, true><<<(M_PAD / 16) * 8, 64, 0, stream>>>(
      sup1, s_meta, row_ptr, b1, perm, a2b, nullptr, M_PAD);

  // layer 2
  gemm2_kernel<<<M_PAD / 128, 256, 0, stream>>>(a2b, w2T, sup2);
  agg_lite_kernel<4, 128, false><<<(N_NODES_C / 16) * 4, 64, 0, stream>>>(
      sup2, s_meta, row_ptr, b2, perm, nullptr, out, N_NODES_C);
}

// Round 3
// 287.599 us; speedup vs baseline: 1.0659x; 1.0659x over previous
//
#include <hip/hip_runtime.h>

#define NEG_SLOPE 0.01f

constexpr int N_NODES_C = 50000;
constexpr int N_EDGES_C = 800000;
constexpr int M_PAD = 50048;      // 391 * 128
constexpr int META_CAP = 950016;  // padded CSR capacity: 800000 + <=150000 pad + slack

typedef short bf16x8 __attribute__((ext_vector_type(8)));
typedef float f32x4 __attribute__((ext_vector_type(4)));

__device__ inline unsigned short f2bf(float f) {
  unsigned int u = __float_as_uint(f);
  u += 0x7FFF + ((u >> 16) & 1);  // round-to-nearest-even
  return (unsigned short)(u >> 16);
}
__device__ inline float bf2f(unsigned int h16) {
  return __uint_as_float(h16 << 16);
}

// ---------------- fused preprocessing ----------------
constexpr int NB_CONVX = (M_PAD * 32) / 256;          // 6256
constexpr int NB_W1 = (256 * 256) / 256;              // 256
constexpr int NB_W2 = (256 * 128) / 256;              // 128
constexpr int NB_HIST = ((N_EDGES_C / 4) + 255) / 256;  // 782
constexpr int NB_PRE = NB_CONVX + NB_W1 + NB_W2 + NB_HIST;

__global__ __launch_bounds__(256) void pre_kernel(
    const float* __restrict__ x, const float* __restrict__ w1,
    const float* __restrict__ w2, const int* __restrict__ dst,
    unsigned short* __restrict__ xb, unsigned short* __restrict__ w1T,
    unsigned short* __restrict__ w2T, int* __restrict__ counts) {
  const int bx = blockIdx.x;
  const int tid = threadIdx.x;
  if (bx < NB_CONVX) {
    int idx = bx * 256 + tid;
    int row = idx >> 5;
    int c8 = (idx & 31) << 3;
    uint4 v;
    if (row < N_NODES_C) {
      const float4* p = (const float4*)(x + (size_t)row * 256 + c8);
      float4 a = p[0], b = p[1];
      v.x = f2bf(a.x) | ((unsigned)f2bf(a.y) << 16);
      v.y = f2bf(a.z) | ((unsigned)f2bf(a.w) << 16);
      v.z = f2bf(b.x) | ((unsigned)f2bf(b.y) << 16);
      v.w = f2bf(b.z) | ((unsigned)f2bf(b.w) << 16);
    } else {
      v = make_uint4(0, 0, 0, 0);
    }
    *(uint4*)(xb + (size_t)row * 256 + c8) = v;
  } else if (bx < NB_CONVX + NB_W1) {
    int idx = (bx - NB_CONVX) * 256 + tid;  // over [N=256][K=256]
    int n = idx >> 8, k = idx & 255;
    w1T[idx] = f2bf(w1[(size_t)k * 256 + n]);
  } else if (bx < NB_CONVX + NB_W1 + NB_W2) {
    int idx = (bx - NB_CONVX - NB_W1) * 256 + tid;  // over [N=128][K=256]
    int n = idx >> 8, k = idx & 255;
    w2T[idx] = f2bf(w2[(size_t)k * 128 + n]);
  } else {
    // 4-edge ILP histogram: independent atomics, vectorized index load
    int g = (bx - NB_CONVX - NB_W1 - NB_W2) * 256 + tid;
    int e = g * 4;
    if (e < N_EDGES_C) {
      int4 d4 = *(const int4*)(dst + e);
      atomicAdd(&counts[d4.x], 1);
      atomicAdd(&counts[d4.y], 1);
      atomicAdd(&counts[d4.z], 1);
      atomicAdd(&counts[d4.w], 1);
    }
  }
}

// ---------------- degree histogram (64 bins, node + padded-edge counts) ----
constexpr int NB_NODE = (N_NODES_C + 255) / 256;  // 196
constexpr int NB_SCAT = (M_PAD + 255) / 256;      // 196

__global__ __launch_bounds__(256) void hist_kernel(const int* __restrict__ counts,
                                                   int* __restrict__ hist2,
                                                   int* __restrict__ ehist) {
  __shared__ int lh[64], le[64];
  const int t = threadIdx.x;
  if (t < 64) { lh[t] = 0; le[t] = 0; }
  __syncthreads();
  const int i = blockIdx.x * 256 + t;
  if (i < N_NODES_C) {
    int d = counts[i];
    int bin = d < 63 ? d : 63;
    atomicAdd(&lh[bin], 1);
    atomicAdd(&le[bin], (d + 3) & ~3);  // 4-aligned (padded) segment length
  }
  __syncthreads();
  if (t < 64) {
    if (lh[t]) atomicAdd(&hist2[t], lh[t]);
    if (le[t]) atomicAdd(&ehist[t], le[t]);
  }
}

// ---------------- degree-sorted permuted-CSR scatter ----------------
// Every block redundantly scans the 64-bin histograms (wave 0), then claims
// per-bin node/edge regions with ONE global atomic per (block,bin).
// Emits: perm (rank->node), nstart/ndeg (rank->segment), cursor (node->fill
// position). Segments are 16B-aligned; pad slots zeroed here.
__global__ __launch_bounds__(256) void scatter_kernel(
    const int* __restrict__ counts, const int* __restrict__ hist2,
    const int* __restrict__ ehist, int* __restrict__ gclaim_n,
    int* __restrict__ gclaim_e, int* __restrict__ perm,
    int* __restrict__ nstart, int* __restrict__ ndeg,
    int* __restrict__ cursor, unsigned* __restrict__ s_meta) {
  __shared__ int nbase[64], ebase[64], lh[64], le[64], gn[64], ge[64];
  const int t = threadIdx.x;
  if (t < 64) {
    int hv = hist2[t], ev = ehist[t];
    int xs = hv, xe = ev;
#pragma unroll
    for (int off = 1; off < 64; off <<= 1) {
      int a = __shfl_up(xs, off);
      int b = __shfl_up(xe, off);
      if (t >= off) { xs += a; xe += b; }
    }
    nbase[t] = xs - hv;  // exclusive bucket base (nodes)
    ebase[t] = xe - ev;  // exclusive bucket base (edge slots)
    lh[t] = 0;
    le[t] = 0;
  }
  __syncthreads();
  const int idx = blockIdx.x * 256 + t;
  int d = -1, bin = 0, lrank = 0, erank = 0;
  if (idx < N_NODES_C) {
    d = counts[idx];
    bin = d < 63 ? d : 63;
    lrank = atomicAdd(&lh[bin], 1);
    erank = atomicAdd(&le[bin], (d + 3) & ~3);
  } else if (idx < M_PAD) {
    perm[idx] = idx;  // padding ranks map to themselves, zero-length segment
    nstart[idx] = 0;
    ndeg[idx] = 0;
  }
  __syncthreads();
  if (t < 64) {
    gn[t] = lh[t] ? nbase[t] + atomicAdd(&gclaim_n[t], lh[t]) : 0;
    ge[t] = le[t] ? ebase[t] + atomicAdd(&gclaim_e[t], le[t]) : 0;
  }
  __syncthreads();
  if (d >= 0) {
    const int grank = gn[bin] + lrank;
    const int estart = ge[bin] + erank;
    perm[grank] = idx;
    nstart[grank] = estart;
    ndeg[grank] = d;
    cursor[idx] = estart;
    const int d4 = (d + 3) & ~3;
    for (int j = d; j < d4; ++j) s_meta[estart + j] = 0;  // zero-weight pads
  }
}

// ---------------- shared GEMM tile (device fn) ----------------
// C_sliced[slice][M_PAD][32] where slice = col/32

#define GLOAD_LDS16(g, l)                                              \
  __builtin_amdgcn_global_load_lds(                                    \
      (__attribute__((address_space(1))) void*)(g),                    \
      (__attribute__((address_space(3))) void*)(l), 16, 0, 0)

__device__ __forceinline__ void gemm_tile(
    const unsigned short* __restrict__ A,   // [M_PAD][256] bf16
    const unsigned short* __restrict__ BT,  // [N][256] bf16
    unsigned short* __restrict__ C,         // [N/32][M_PAD][32] sliced
    int N, int row0, int col0, short* Asm, short* Bsm) {
  constexpr int K = 256;
  const int tid = threadIdx.x;
  const int lane = tid & 63, wave = tid >> 6;
  const int wm = wave & 1, wn = wave >> 1;

  const int ch0 = wave * 2, ch1 = wave * 2 + 1;
  const int o0 = ch0 * 512 + lane * 8;
  const int o1 = ch1 * 512 + lane * 8;
  const int r0 = o0 >> 5, c0 = o0 & 31;
  const int r1 = o1 >> 5, c1 = o1 & 31;

  f32x4 acc[4][4] = {};

  for (int k0 = 0; k0 < K; k0 += 32) {
    GLOAD_LDS16(A + (size_t)(row0 + r0) * K + k0 + c0, &Asm[ch0 * 512]);
    GLOAD_LDS16(A + (size_t)(row0 + r1) * K + k0 + c1, &Asm[ch1 * 512]);
    GLOAD_LDS16(BT + (size_t)(col0 + r0) * K + k0 + c0, &Bsm[ch0 * 512]);
    GLOAD_LDS16(BT + (size_t)(col0 + r1) * K + k0 + c1, &Bsm[ch1 * 512]);
    __builtin_amdgcn_s_waitcnt(0);
    __syncthreads();

    bf16x8 af[4], bf[4];
#pragma unroll
    for (int mt = 0; mt < 4; ++mt)
      af[mt] = *(const bf16x8*)&Asm[(wm * 64 + mt * 16 + (lane & 15)) * 32 + (lane >> 4) * 8];
#pragma unroll
    for (int nt = 0; nt < 4; ++nt)
      bf[nt] = *(const bf16x8*)&Bsm[(wn * 64 + nt * 16 + (lane & 15)) * 32 + (lane >> 4) * 8];
#pragma unroll
    for (int mt = 0; mt < 4; ++mt)
#pragma unroll
      for (int nt = 0; nt < 4; ++nt)
        acc[mt][nt] = __builtin_amdgcn_mfma_f32_16x16x32_bf16(af[mt], bf[nt], acc[mt][nt], 0, 0, 0);
    __syncthreads();
  }

  const int cl = lane & 15, rq = (lane >> 4) * 4;
#pragma unroll
  for (int mt = 0; mt < 4; ++mt) {
    const int rbase = row0 + wm * 64 + mt * 16 + rq;
#pragma unroll
    for (int nt = 0; nt < 4; ++nt) {
      const int col = col0 + wn * 64 + nt * 16 + cl;
      const size_t sbase = ((size_t)(col >> 5) * M_PAD) * 32 + (col & 31);
#pragma unroll
      for (int i = 0; i < 4; ++i)
        C[sbase + (size_t)(rbase + i) * 32] = f2bf(acc[mt][nt][i]);
    }
  }
}

// ---------------- fused fill + gemm1 ----------------
// Even blocks: gemm1 tiles; odd blocks: CSR bucket fill (4 edges/thread).
// cursor pre-initialized to permuted-CSR segment starts -> s_meta lands in
// degree-sorted contiguous layout. meta packed 4B: src(u16) | bf16(ew)<<16
constexpr int NB_GEMM1 = 2 * (M_PAD / 128);              // 782
constexpr int NB_FILL = ((N_EDGES_C / 4) + 255) / 256;   // 782 (== NB_GEMM1)

__global__ __launch_bounds__(256) void fill_gemm1_kernel(
    const unsigned short* __restrict__ A, const unsigned short* __restrict__ BT,
    unsigned short* __restrict__ C, const int* __restrict__ src,
    const int* __restrict__ dst, const float* __restrict__ ew,
    int* __restrict__ cursor, unsigned* __restrict__ s_meta) {
  __shared__ short Asm[128 * 32];
  __shared__ short Bsm[128 * 32];
  const int b = blockIdx.x;
  if ((b & 1) == 0) {
    const int t = b >> 1;  // [0, NB_GEMM1)
    gemm_tile(A, BT, C, 256, (t >> 1) * 128, (t & 1) * 128, Asm, Bsm);
  } else {
    const int g = (b >> 1) * 256 + threadIdx.x;  // 4-edge group id
    const int e = g * 4;
    if (e < N_EDGES_C) {
      int4 d4 = *(const int4*)(dst + e);
      int4 s4 = *(const int4*)(src + e);
      float4 w4 = *(const float4*)(ew + e);
      unsigned m0 = (unsigned)s4.x | ((unsigned)f2bf(w4.x) << 16);
      unsigned m1 = (unsigned)s4.y | ((unsigned)f2bf(w4.y) << 16);
      unsigned m2 = (unsigned)s4.z | ((unsigned)f2bf(w4.z) << 16);
      unsigned m3 = (unsigned)s4.w | ((unsigned)f2bf(w4.w) << 16);
      int p0 = atomicAdd(&cursor[d4.x], 1);
      int p1 = atomicAdd(&cursor[d4.y], 1);
      int p2 = atomicAdd(&cursor[d4.z], 1);
      int p3 = atomicAdd(&cursor[d4.w], 1);
      __builtin_nontemporal_store(m0, s_meta + p0);
      __builtin_nontemporal_store(m1, s_meta + p1);
      __builtin_nontemporal_store(m2, s_meta + p2);
      __builtin_nontemporal_store(m3, s_meta + p3);
    }
  }
}

__global__ __launch_bounds__(256) void gemm2_kernel(
    const unsigned short* __restrict__ A, const unsigned short* __restrict__ BT,
    unsigned short* __restrict__ C) {
  __shared__ short Asm[128 * 32];
  __shared__ short Bsm[128 * 32];
  gemm_tile(A, BT, C, 128, blockIdx.x * 128, 0, Asm, Bsm);
}

// ---------------- lite sliced aggregation (permuted CSR) ----------------
// ONE WAVE per block = 16 quad-nodes; slice = bx & (NSLICE-1); degree-sorted
// ranks -> uniform trip counts AND contiguous s_meta windows (L2-friendly).
// Segments 16B-aligned -> uint4 meta loads (4 edges); inner loop software-
// pipelined 8 edges deep: prefetch next 2 meta quads while gathering current.

__device__ inline void fma8(float* acc, uint4 v, float wt) {
  acc[0] += bf2f(v.x & 0xffffu) * wt;
  acc[1] += bf2f(v.x >> 16) * wt;
  acc[2] += bf2f(v.y & 0xffffu) * wt;
  acc[3] += bf2f(v.y >> 16) * wt;
  acc[4] += bf2f(v.z & 0xffffu) * wt;
  acc[5] += bf2f(v.z >> 16) * wt;
  acc[6] += bf2f(v.w & 0xffffu) * wt;
  acc[7] += bf2f(v.w >> 16) * wt;
}

__device__ __forceinline__ void gfma4(float* acc, uint4 m,
                                      const unsigned short* __restrict__ tab,
                                      int dimg) {
  uint4 v0 = *(const uint4*)(tab + (m.x & 0xffffu) * 32 + dimg * 8);
  uint4 v1 = *(const uint4*)(tab + (m.y & 0xffffu) * 32 + dimg * 8);
  uint4 v2 = *(const uint4*)(tab + (m.z & 0xffffu) * 32 + dimg * 8);
  uint4 v3 = *(const uint4*)(tab + (m.w & 0xffffu) * 32 + dimg * 8);
  fma8(acc, v0, bf2f(m.x >> 16));
  fma8(acc, v1, bf2f(m.y >> 16));
  fma8(acc, v2, bf2f(m.z >> 16));
  fma8(acc, v3, bf2f(m.w >> 16));
}

template <int NSLICE, int OUT_D, bool OUT_BF16>
__global__ __launch_bounds__(64) void agg_lite_kernel(
    const unsigned short* __restrict__ supS,  // [NSLICE][M_PAD][32]
    const unsigned* __restrict__ s_meta,      // permuted CSR, 4-aligned segs
    const int* __restrict__ nstart, const int* __restrict__ ndeg,
    const int* __restrict__ perm, const float* __restrict__ bias,
    unsigned short* __restrict__ out_bf, float* __restrict__ out_f, int n_total) {
  const int bx = blockIdx.x;
  const int slice = bx & (NSLICE - 1);
  const int group = bx / NSLICE;
  const int lane = threadIdx.x;  // 0..63
  const int quad = lane >> 2;    // node within group (0..15)
  const int dimg = lane & 3;     // 8-dim octet within 32-dim slice
  const int idx = group * 16 + quad;
  if (idx >= n_total) return;
  const int n = perm[idx];
  const bool valid = n < N_NODES_C;
  const unsigned short* tab = supS + (size_t)slice * M_PAD * 32;

  float acc[8] = {};
  const int s = nstart[idx];
  const int nq = (ndeg[idx] + 3) >> 2;  // 4-edge quads (pads are zero-weight)
  const uint4* mp = (const uint4*)(s_meta + s);

  if (nq > 0) {
    uint4 m0 = mp[0];
    uint4 m1 = (nq > 1) ? mp[1] : make_uint4(0, 0, 0, 0);
    int q = 0;
    for (; q + 2 < nq; q += 2) {
      uint4 p0 = mp[q + 2];
      uint4 p1 = mp[q + 3];  // may read 16B past segment end (buffer slack)
      gfma4(acc, m0, tab, dimg);
      gfma4(acc, m1, tab, dimg);
      m0 = p0;
      m1 = p1;
    }
    gfma4(acc, m0, tab, dimg);
    if (q + 1 < nq) gfma4(acc, m1, tab, dimg);
  }

  const int dbase = slice * 32 + dimg * 8;
  if (OUT_BF16) {
    unsigned short o[8];
#pragma unroll
    for (int j = 0; j < 8; ++j) {
      if (valid) {
        float v = acc[j] + bias[dbase + j];
        v = v >= 0.f ? v : NEG_SLOPE * v;
        o[j] = f2bf(v);
      } else {
        o[j] = 0;
      }
    }
    uint4 pk;
    pk.x = o[0] | ((unsigned)o[1] << 16);
    pk.y = o[2] | ((unsigned)o[3] << 16);
    pk.z = o[4] | ((unsigned)o[5] << 16);
    pk.w = o[6] | ((unsigned)o[7] << 16);
    *(uint4*)(out_bf + (size_t)n * OUT_D + dbase) = pk;
  } else if (valid) {
    float r[8];
#pragma unroll
    for (int j = 0; j < 8; ++j) {
      float v = acc[j] + bias[dbase + j];
      r[j] = v >= 0.f ? v : NEG_SLOPE * v;
    }
    *(float4*)(out_f + (size_t)n * OUT_D + dbase) = make_float4(r[0], r[1], r[2], r[3]);
    *(float4*)(out_f + (size_t)n * OUT_D + dbase + 4) = make_float4(r[4], r[5], r[6], r[7]);
  }
}

// ---------------- launch ----------------

extern "C" void kernel_launch(void* const* d_in, const int* in_sizes, int n_in,
                              void* d_out, int out_size, void* d_ws, size_t ws_size,
                              hipStream_t stream) {
  const float* x  = (const float*)d_in[0];   // [50000,256]
  const float* w1 = (const float*)d_in[1];   // [256,256]
  const float* b1 = (const float*)d_in[2];   // [256]
  const float* w2 = (const float*)d_in[3];   // [256,128]
  const float* b2 = (const float*)d_in[4];   // [128]
  const int*   src = (const int*)d_in[5];    // [800000]
  const int*   dst = (const int*)d_in[6];    // [800000]
  const float* ew  = (const float*)d_in[7];  // [800000]
  float* out = (float*)d_out;                // [50000,128]

  unsigned short* xb   = (unsigned short*)d_ws;              // M_PAD*256
  unsigned short* a2b  = xb + (size_t)M_PAD * 256;           // M_PAD*256
  unsigned short* sup1 = a2b + (size_t)M_PAD * 256;          // 8 x [M_PAD][32]
  unsigned short* sup2 = sup1 + (size_t)M_PAD * 256;         // 4 x [M_PAD][32]
  unsigned short* w1T  = sup2 + (size_t)M_PAD * 128;         // 256*256
  unsigned short* w2T  = w1T + 256 * 256;                    // 128*256
  int* counts  = (int*)(w2T + 128 * 256);                    // 50000
  int* cursor  = counts + N_NODES_C;                         // 50000
  int* perm    = cursor + N_NODES_C;                         // M_PAD
  int* nstart  = perm + M_PAD;                               // M_PAD
  int* ndeg    = nstart + M_PAD;                             // M_PAD
  int* hist2   = ndeg + M_PAD;                               // 64
  int* ehist   = hist2 + 64;                                 // 64
  int* gclaim_n= ehist + 64;                                 // 64
  int* gclaim_e= gclaim_n + 64;                              // 64
  unsigned* s_meta = (unsigned*)(gclaim_e + 64);             // META_CAP * 4B

  // zero counts + {hist2, ehist, gclaim_n, gclaim_e} (contiguous 256 ints)
  hipMemsetAsync(counts, 0, N_NODES_C * sizeof(int), stream);
  hipMemsetAsync(hist2, 0, 256 * sizeof(int), stream);
  pre_kernel<<<NB_PRE, 256, 0, stream>>>(x, w1, w2, dst, xb, w1T, w2T, counts);

  // degree histogram -> permuted-CSR scatter (rank/segment assignment)
  hist_kernel<<<NB_NODE, 256, 0, stream>>>(counts, hist2, ehist);
  scatter_kernel<<<NB_SCAT, 256, 0, stream>>>(counts, hist2, ehist, gclaim_n,
                                              gclaim_e, perm, nstart, ndeg,
                                              cursor, s_meta);

  // fused: CSR bucket fill (into permuted layout) + gemm1 (one dispatch)
  fill_gemm1_kernel<<<NB_GEMM1 + NB_FILL, 256, 0, stream>>>(
      xb, w1T, sup1, src, dst, ew, cursor, s_meta);

  // layer-1 aggregation -> a2b (bf16, lrelu+bias fused)
  agg_lite_kernel<8, 256, true><<<(M_PAD / 16) * 8, 64, 0, stream>>>(
      sup1, s_meta, nstart, ndeg, perm, b1, a2b, nullptr, M_PAD);

  // layer 2
  gemm2_kernel<<<M_PAD / 128, 256, 0, stream>>>(a2b, w2T, sup2);
  agg_lite_kernel<4, 128, false><<<(N_NODES_C / 16) * 4, 64, 0, stream>>>(
      sup2, s_meta, nstart, ndeg, perm, b2, nullptr, out, N_NODES_C);
}

// Round 4
// 283.294 us; speedup vs baseline: 1.0821x; 1.0152x over previous
//
#include <hip/hip_runtime.h>

#define NEG_SLOPE 0.01f

constexpr int N_NODES_C = 50000;
constexpr int N_EDGES_C = 800000;
constexpr int M_PAD = 50048;      // 391 * 128
constexpr int META_CAP = 950016;  // padded CSR capacity: 800000 + <=150000 pad + slack

typedef short bf16x8 __attribute__((ext_vector_type(8)));
typedef float f32x4 __attribute__((ext_vector_type(4)));

__device__ inline unsigned short f2bf(float f) {
  unsigned int u = __float_as_uint(f);
  u += 0x7FFF + ((u >> 16) & 1);  // round-to-nearest-even
  return (unsigned short)(u >> 16);
}
__device__ inline float bf2f(unsigned int h16) {
  return __uint_as_float(h16 << 16);
}

// ---------------- fused preprocessing ----------------
// conv: 128B/thread (8 independent float4 loads -> deep MLP).
// histogram blocks INTERLEAVED with conv blocks (alternating over the first
// 2*NB_HIST blocks) so random-atomic latency hides under streaming conv.
constexpr int NB_CONVX = (M_PAD * 8) / 256;             // 1564
constexpr int NB_W1 = (256 * 256) / 256;                // 256
constexpr int NB_W2 = (256 * 128) / 256;                // 128
constexpr int NB_HIST = ((N_EDGES_C / 4) + 255) / 256;  // 782
constexpr int NB_NONH = NB_CONVX + NB_W1 + NB_W2;       // 1948
constexpr int NB_PRE = NB_NONH + NB_HIST;               // 2730
constexpr int NB_IL = 2 * NB_HIST;                      // 1564 interleaved region

__global__ __launch_bounds__(256) void pre_kernel(
    const float* __restrict__ x, const float* __restrict__ w1,
    const float* __restrict__ w2, const int* __restrict__ dst,
    unsigned short* __restrict__ xb, unsigned short* __restrict__ w1T,
    unsigned short* __restrict__ w2T, int* __restrict__ counts) {
  const int bx = blockIdx.x;
  const int tid = threadIdx.x;
  int l = 0, isHist = 0, h = 0;
  if (bx < NB_IL) {
    if (bx & 1) { isHist = 1; h = bx >> 1; }
    else l = bx >> 1;
  } else {
    l = bx - NB_HIST;
  }

  if (isHist) {
    // 4-edge ILP histogram: independent atomics, vectorized index load
    int e = (h * 256 + tid) * 4;
    if (e < N_EDGES_C) {
      int4 d4 = *(const int4*)(dst + e);
      atomicAdd(&counts[d4.x], 1);
      atomicAdd(&counts[d4.y], 1);
      atomicAdd(&counts[d4.z], 1);
      atomicAdd(&counts[d4.w], 1);
    }
  } else if (l < NB_CONVX) {
    // 32 dims (128B in / 64B out) per thread
    int idx = l * 256 + tid;
    int row = idx >> 3;
    int c32 = (idx & 7) * 32;
    uint4 o[4];
    if (row < N_NODES_C) {
      const float4* p = (const float4*)(x + (size_t)row * 256 + c32);
      float4 f[8];
#pragma unroll
      for (int i = 0; i < 8; ++i) f[i] = p[i];
#pragma unroll
      for (int i = 0; i < 4; ++i) {
        o[i].x = f2bf(f[2 * i].x) | ((unsigned)f2bf(f[2 * i].y) << 16);
        o[i].y = f2bf(f[2 * i].z) | ((unsigned)f2bf(f[2 * i].w) << 16);
        o[i].z = f2bf(f[2 * i + 1].x) | ((unsigned)f2bf(f[2 * i + 1].y) << 16);
        o[i].w = f2bf(f[2 * i + 1].z) | ((unsigned)f2bf(f[2 * i + 1].w) << 16);
      }
    } else {
#pragma unroll
      for (int i = 0; i < 4; ++i) o[i] = make_uint4(0, 0, 0, 0);
    }
#pragma unroll
    for (int i = 0; i < 4; ++i)
      *(uint4*)(xb + (size_t)row * 256 + c32 + i * 8) = o[i];
  } else if (l < NB_CONVX + NB_W1) {
    int idx = (l - NB_CONVX) * 256 + tid;  // over [N=256][K=256]
    int n = idx >> 8, k = idx & 255;
    w1T[idx] = f2bf(w1[(size_t)k * 256 + n]);
  } else {
    int idx = (l - NB_CONVX - NB_W1) * 256 + tid;  // over [N=128][K=256]
    int n = idx >> 8, k = idx & 255;
    w2T[idx] = f2bf(w2[(size_t)k * 128 + n]);
  }
}

// ---------------- degree histogram (64 bins, node + padded-edge counts) ----
constexpr int NB_NODE = (N_NODES_C + 255) / 256;  // 196
constexpr int NB_SCAT = (M_PAD + 255) / 256;      // 196

__global__ __launch_bounds__(256) void hist_kernel(const int* __restrict__ counts,
                                                   int* __restrict__ hist2,
                                                   int* __restrict__ ehist) {
  __shared__ int lh[64], le[64];
  const int t = threadIdx.x;
  if (t < 64) { lh[t] = 0; le[t] = 0; }
  __syncthreads();
  const int i = blockIdx.x * 256 + t;
  if (i < N_NODES_C) {
    int d = counts[i];
    int bin = d < 63 ? d : 63;
    atomicAdd(&lh[bin], 1);
    atomicAdd(&le[bin], (d + 3) & ~3);  // 4-aligned (padded) segment length
  }
  __syncthreads();
  if (t < 64) {
    if (lh[t]) atomicAdd(&hist2[t], lh[t]);
    if (le[t]) atomicAdd(&ehist[t], le[t]);
  }
}

// ---------------- degree-sorted permuted-CSR scatter ----------------
// Every block redundantly scans the 64-bin histograms (wave 0), then claims
// per-bin node/edge regions with ONE global atomic per (block,bin).
// Emits: perm (rank->node), nstart/ndeg (rank->segment), cursor (node->fill
// position). Segments are 16B-aligned; pad slots zeroed here.
__global__ __launch_bounds__(256) void scatter_kernel(
    const int* __restrict__ counts, const int* __restrict__ hist2,
    const int* __restrict__ ehist, int* __restrict__ gclaim_n,
    int* __restrict__ gclaim_e, int* __restrict__ perm,
    int* __restrict__ nstart, int* __restrict__ ndeg,
    int* __restrict__ cursor, unsigned* __restrict__ s_meta) {
  __shared__ int nbase[64], ebase[64], lh[64], le[64], gn[64], ge[64];
  const int t = threadIdx.x;
  if (t < 64) {
    int hv = hist2[t], ev = ehist[t];
    int xs = hv, xe = ev;
#pragma unroll
    for (int off = 1; off < 64; off <<= 1) {
      int a = __shfl_up(xs, off);
      int b = __shfl_up(xe, off);
      if (t >= off) { xs += a; xe += b; }
    }
    nbase[t] = xs - hv;  // exclusive bucket base (nodes)
    ebase[t] = xe - ev;  // exclusive bucket base (edge slots)
    lh[t] = 0;
    le[t] = 0;
  }
  __syncthreads();
  const int idx = blockIdx.x * 256 + t;
  int d = -1, bin = 0, lrank = 0, erank = 0;
  if (idx < N_NODES_C) {
    d = counts[idx];
    bin = d < 63 ? d : 63;
    lrank = atomicAdd(&lh[bin], 1);
    erank = atomicAdd(&le[bin], (d + 3) & ~3);
  } else if (idx < M_PAD) {
    perm[idx] = idx;  // padding ranks map to themselves, zero-length segment
    nstart[idx] = 0;
    ndeg[idx] = 0;
  }
  __syncthreads();
  if (t < 64) {
    gn[t] = lh[t] ? nbase[t] + atomicAdd(&gclaim_n[t], lh[t]) : 0;
    ge[t] = le[t] ? ebase[t] + atomicAdd(&gclaim_e[t], le[t]) : 0;
  }
  __syncthreads();
  if (d >= 0) {
    const int grank = gn[bin] + lrank;
    const int estart = ge[bin] + erank;
    perm[grank] = idx;
    nstart[grank] = estart;
    ndeg[grank] = d;
    cursor[idx] = estart;
    const int d4 = (d + 3) & ~3;
    for (int j = d; j < d4; ++j) s_meta[estart + j] = 0;  // zero-weight pads
  }
}

// ---------------- shared GEMM tile (device fn) ----------------
// C_sliced[slice][M_PAD][32] where slice = col/32

#define GLOAD_LDS16(g, l)                                              \
  __builtin_amdgcn_global_load_lds(                                    \
      (__attribute__((address_space(1))) void*)(g),                    \
      (__attribute__((address_space(3))) void*)(l), 16, 0, 0)

__device__ __forceinline__ void gemm_tile(
    const unsigned short* __restrict__ A,   // [M_PAD][256] bf16
    const unsigned short* __restrict__ BT,  // [N][256] bf16
    unsigned short* __restrict__ C,         // [N/32][M_PAD][32] sliced
    int N, int row0, int col0, short* Asm, short* Bsm) {
  constexpr int K = 256;
  const int tid = threadIdx.x;
  const int lane = tid & 63, wave = tid >> 6;
  const int wm = wave & 1, wn = wave >> 1;

  const int ch0 = wave * 2, ch1 = wave * 2 + 1;
  const int o0 = ch0 * 512 + lane * 8;
  const int o1 = ch1 * 512 + lane * 8;
  const int r0 = o0 >> 5, c0 = o0 & 31;
  const int r1 = o1 >> 5, c1 = o1 & 31;

  f32x4 acc[4][4] = {};

  for (int k0 = 0; k0 < K; k0 += 32) {
    GLOAD_LDS16(A + (size_t)(row0 + r0) * K + k0 + c0, &Asm[ch0 * 512]);
    GLOAD_LDS16(A + (size_t)(row0 + r1) * K + k0 + c1, &Asm[ch1 * 512]);
    GLOAD_LDS16(BT + (size_t)(col0 + r0) * K + k0 + c0, &Bsm[ch0 * 512]);
    GLOAD_LDS16(BT + (size_t)(col0 + r1) * K + k0 + c1, &Bsm[ch1 * 512]);
    __builtin_amdgcn_s_waitcnt(0);
    __syncthreads();

    bf16x8 af[4], bf[4];
#pragma unroll
    for (int mt = 0; mt < 4; ++mt)
      af[mt] = *(const bf16x8*)&Asm[(wm * 64 + mt * 16 + (lane & 15)) * 32 + (lane >> 4) * 8];
#pragma unroll
    for (int nt = 0; nt < 4; ++nt)
      bf[nt] = *(const bf16x8*)&Bsm[(wn * 64 + nt * 16 + (lane & 15)) * 32 + (lane >> 4) * 8];
#pragma unroll
    for (int mt = 0; mt < 4; ++mt)
#pragma unroll
      for (int nt = 0; nt < 4; ++nt)
        acc[mt][nt] = __builtin_amdgcn_mfma_f32_16x16x32_bf16(af[mt], bf[nt], acc[mt][nt], 0, 0, 0);
    __syncthreads();
  }

  const int cl = lane & 15, rq = (lane >> 4) * 4;
#pragma unroll
  for (int mt = 0; mt < 4; ++mt) {
    const int rbase = row0 + wm * 64 + mt * 16 + rq;
#pragma unroll
    for (int nt = 0; nt < 4; ++nt) {
      const int col = col0 + wn * 64 + nt * 16 + cl;
      const size_t sbase = ((size_t)(col >> 5) * M_PAD) * 32 + (col & 31);
#pragma unroll
      for (int i = 0; i < 4; ++i)
        C[sbase + (size_t)(rbase + i) * 32] = f2bf(acc[mt][nt][i]);
    }
  }
}

// ---------------- fused fill + gemm1 ----------------
// Even blocks: gemm1 tiles; odd blocks: CSR bucket fill (4 edges/thread).
// cursor pre-initialized to permuted-CSR segment starts -> s_meta lands in
// degree-sorted contiguous layout. meta packed 4B: src(u16) | bf16(ew)<<16
constexpr int NB_GEMM1 = 2 * (M_PAD / 128);              // 782
constexpr int NB_FILL = ((N_EDGES_C / 4) + 255) / 256;   // 782 (== NB_GEMM1)

__global__ __launch_bounds__(256) void fill_gemm1_kernel(
    const unsigned short* __restrict__ A, const unsigned short* __restrict__ BT,
    unsigned short* __restrict__ C, const int* __restrict__ src,
    const int* __restrict__ dst, const float* __restrict__ ew,
    int* __restrict__ cursor, unsigned* __restrict__ s_meta) {
  __shared__ short Asm[128 * 32];
  __shared__ short Bsm[128 * 32];
  const int b = blockIdx.x;
  if ((b & 1) == 0) {
    const int t = b >> 1;  // [0, NB_GEMM1)
    gemm_tile(A, BT, C, 256, (t >> 1) * 128, (t & 1) * 128, Asm, Bsm);
  } else {
    const int g = (b >> 1) * 256 + threadIdx.x;  // 4-edge group id
    const int e = g * 4;
    if (e < N_EDGES_C) {
      int4 d4 = *(const int4*)(dst + e);
      int4 s4 = *(const int4*)(src + e);
      float4 w4 = *(const float4*)(ew + e);
      unsigned m0 = (unsigned)s4.x | ((unsigned)f2bf(w4.x) << 16);
      unsigned m1 = (unsigned)s4.y | ((unsigned)f2bf(w4.y) << 16);
      unsigned m2 = (unsigned)s4.z | ((unsigned)f2bf(w4.z) << 16);
      unsigned m3 = (unsigned)s4.w | ((unsigned)f2bf(w4.w) << 16);
      int p0 = atomicAdd(&cursor[d4.x], 1);
      int p1 = atomicAdd(&cursor[d4.y], 1);
      int p2 = atomicAdd(&cursor[d4.z], 1);
      int p3 = atomicAdd(&cursor[d4.w], 1);
      __builtin_nontemporal_store(m0, s_meta + p0);
      __builtin_nontemporal_store(m1, s_meta + p1);
      __builtin_nontemporal_store(m2, s_meta + p2);
      __builtin_nontemporal_store(m3, s_meta + p3);
    }
  }
}

__global__ __launch_bounds__(256) void gemm2_kernel(
    const unsigned short* __restrict__ A, const unsigned short* __restrict__ BT,
    unsigned short* __restrict__ C) {
  __shared__ short Asm[128 * 32];
  __shared__ short Bsm[128 * 32];
  gemm_tile(A, BT, C, 128, blockIdx.x * 128, 0, Asm, Bsm);
}

// ---------------- lite sliced aggregation (permuted CSR) ----------------
// 256-thread blocks = 4 waves x 16 quad-nodes, ALL SAME SLICE (keeps the
// slice<->XCD L2 pinning via slice = bx & (NSLICE-1)) -- one-wave workgroups
// capped occupancy at ~45% (workgroup-slot limit); 4-wave blocks pack the CU.
// Degree-sorted ranks -> uniform trip counts AND contiguous s_meta windows.
// Segments 16B-aligned -> uint4 meta loads; loop pipelined 8 edges deep.

__device__ inline void fma8(float* acc, uint4 v, float wt) {
  acc[0] += bf2f(v.x & 0xffffu) * wt;
  acc[1] += bf2f(v.x >> 16) * wt;
  acc[2] += bf2f(v.y & 0xffffu) * wt;
  acc[3] += bf2f(v.y >> 16) * wt;
  acc[4] += bf2f(v.z & 0xffffu) * wt;
  acc[5] += bf2f(v.z >> 16) * wt;
  acc[6] += bf2f(v.w & 0xffffu) * wt;
  acc[7] += bf2f(v.w >> 16) * wt;
}

__device__ __forceinline__ void gfma4(float* acc, uint4 m,
                                      const unsigned short* __restrict__ tab,
                                      int dimg) {
  uint4 v0 = *(const uint4*)(tab + (m.x & 0xffffu) * 32 + dimg * 8);
  uint4 v1 = *(const uint4*)(tab + (m.y & 0xffffu) * 32 + dimg * 8);
  uint4 v2 = *(const uint4*)(tab + (m.z & 0xffffu) * 32 + dimg * 8);
  uint4 v3 = *(const uint4*)(tab + (m.w & 0xffffu) * 32 + dimg * 8);
  fma8(acc, v0, bf2f(m.x >> 16));
  fma8(acc, v1, bf2f(m.y >> 16));
  fma8(acc, v2, bf2f(m.z >> 16));
  fma8(acc, v3, bf2f(m.w >> 16));
}

template <int NSLICE, int OUT_D, bool OUT_BF16>
__global__ __launch_bounds__(256) void agg_lite_kernel(
    const unsigned short* __restrict__ supS,  // [NSLICE][M_PAD][32]
    const unsigned* __restrict__ s_meta,      // permuted CSR, 4-aligned segs
    const int* __restrict__ nstart, const int* __restrict__ ndeg,
    const int* __restrict__ perm, const float* __restrict__ bias,
    unsigned short* __restrict__ out_bf, float* __restrict__ out_f, int n_total) {
  const int bx = blockIdx.x;
  const int slice = bx & (NSLICE - 1);
  const int group = bx / NSLICE;  // 64-node group
  const int tid = threadIdx.x;
  const int wv = tid >> 6;        // wave in block (0..3)
  const int quad = (tid & 63) >> 2;
  const int dimg = tid & 3;       // 8-dim octet within 32-dim slice
  const int idx = group * 64 + wv * 16 + quad;
  if (idx >= n_total) return;
  const int n = perm[idx];
  const bool valid = n < N_NODES_C;
  const unsigned short* tab = supS + (size_t)slice * M_PAD * 32;

  float acc[8] = {};
  const int s = nstart[idx];
  const int nq = (ndeg[idx] + 3) >> 2;  // 4-edge quads (pads are zero-weight)
  const uint4* mp = (const uint4*)(s_meta + s);

  if (nq > 0) {
    uint4 m0 = mp[0];
    uint4 m1 = (nq > 1) ? mp[1] : make_uint4(0, 0, 0, 0);
    int q = 0;
    for (; q + 2 < nq; q += 2) {
      uint4 p0 = mp[q + 2];
      uint4 p1 = mp[q + 3];  // may read 16B past segment end (buffer slack)
      gfma4(acc, m0, tab, dimg);
      gfma4(acc, m1, tab, dimg);
      m0 = p0;
      m1 = p1;
    }
    gfma4(acc, m0, tab, dimg);
    if (q + 1 < nq) gfma4(acc, m1, tab, dimg);
  }

  const int dbase = slice * 32 + dimg * 8;
  if (OUT_BF16) {
    unsigned short o[8];
#pragma unroll
    for (int j = 0; j < 8; ++j) {
      if (valid) {
        float v = acc[j] + bias[dbase + j];
        v = v >= 0.f ? v : NEG_SLOPE * v;
        o[j] = f2bf(v);
      } else {
        o[j] = 0;
      }
    }
    uint4 pk;
    pk.x = o[0] | ((unsigned)o[1] << 16);
    pk.y = o[2] | ((unsigned)o[3] << 16);
    pk.z = o[4] | ((unsigned)o[5] << 16);
    pk.w = o[6] | ((unsigned)o[7] << 16);
    *(uint4*)(out_bf + (size_t)n * OUT_D + dbase) = pk;
  } else if (valid) {
    float r[8];
#pragma unroll
    for (int j = 0; j < 8; ++j) {
      float v = acc[j] + bias[dbase + j];
      r[j] = v >= 0.f ? v : NEG_SLOPE * v;
    }
    *(float4*)(out_f + (size_t)n * OUT_D + dbase) = make_float4(r[0], r[1], r[2], r[3]);
    *(float4*)(out_f + (size_t)n * OUT_D + dbase + 4) = make_float4(r[4], r[5], r[6], r[7]);
  }
}

// ---------------- launch ----------------

extern "C" void kernel_launch(void* const* d_in, const int* in_sizes, int n_in,
                              void* d_out, int out_size, void* d_ws, size_t ws_size,
                              hipStream_t stream) {
  const float* x  = (const float*)d_in[0];   // [50000,256]
  const float* w1 = (const float*)d_in[1];   // [256,256]
  const float* b1 = (const float*)d_in[2];   // [256]
  const float* w2 = (const float*)d_in[3];   // [256,128]
  const float* b2 = (const float*)d_in[4];   // [128]
  const int*   src = (const int*)d_in[5];    // [800000]
  const int*   dst = (const int*)d_in[6];    // [800000]
  const float* ew  = (const float*)d_in[7];  // [800000]
  float* out = (float*)d_out;                // [50000,128]

  unsigned short* xb   = (unsigned short*)d_ws;              // M_PAD*256
  unsigned short* a2b  = xb + (size_t)M_PAD * 256;           // M_PAD*256
  unsigned short* sup1 = a2b + (size_t)M_PAD * 256;          // 8 x [M_PAD][32]
  unsigned short* sup2 = sup1 + (size_t)M_PAD * 256;         // 4 x [M_PAD][32]
  unsigned short* w1T  = sup2 + (size_t)M_PAD * 128;         // 256*256
  unsigned short* w2T  = w1T + 256 * 256;                    // 128*256
  int* counts  = (int*)(w2T + 128 * 256);                    // 50000
  int* cursor  = counts + N_NODES_C;                         // 50000
  int* perm    = cursor + N_NODES_C;                         // M_PAD
  int* nstart  = perm + M_PAD;                               // M_PAD
  int* ndeg    = nstart + M_PAD;                             // M_PAD
  int* hist2   = ndeg + M_PAD;                               // 64
  int* ehist   = hist2 + 64;                                 // 64
  int* gclaim_n= ehist + 64;                                 // 64
  int* gclaim_e= gclaim_n + 64;                              // 64
  unsigned* s_meta = (unsigned*)(gclaim_e + 64);             // META_CAP * 4B

  // zero counts + {hist2, ehist, gclaim_n, gclaim_e} (contiguous 256 ints)
  hipMemsetAsync(counts, 0, N_NODES_C * sizeof(int), stream);
  hipMemsetAsync(hist2, 0, 256 * sizeof(int), stream);
  pre_kernel<<<NB_PRE, 256, 0, stream>>>(x, w1, w2, dst, xb, w1T, w2T, counts);

  // degree histogram -> permuted-CSR scatter (rank/segment assignment)
  hist_kernel<<<NB_NODE, 256, 0, stream>>>(counts, hist2, ehist);
  scatter_kernel<<<NB_SCAT, 256, 0, stream>>>(counts, hist2, ehist, gclaim_n,
                                              gclaim_e, perm, nstart, ndeg,
                                              cursor, s_meta);

  // fused: CSR bucket fill (into permuted layout) + gemm1 (one dispatch)
  fill_gemm1_kernel<<<NB_GEMM1 + NB_FILL, 256, 0, stream>>>(
      xb, w1T, sup1, src, dst, ew, cursor, s_meta);

  // layer-1 aggregation -> a2b (bf16, lrelu+bias fused)
  agg_lite_kernel<8, 256, true><<<(M_PAD / 64) * 8, 256, 0, stream>>>(
      sup1, s_meta, nstart, ndeg, perm, b1, a2b, nullptr, M_PAD);

  // layer 2
  gemm2_kernel<<<M_PAD / 128, 256, 0, stream>>>(a2b, w2T, sup2);
  agg_lite_kernel<4, 128, false><<<((N_NODES_C + 63) / 64) * 4, 256, 0, stream>>>(
      sup2, s_meta, nstart, ndeg, perm, b2, nullptr, out, N_NODES_C);
}